// Round 1
// baseline (596.632 us; speedup 1.0000x reference)
//
#include <hip/hip_runtime.h>
#include <hip/hip_bf16.h>
#include <math.h>

#define S_LEN 2048
#define DMODEL 2048
#define NH 16
#define NKVH 4
#define HDIM 128
#define WINDOW 1024

typedef __bf16 bf16;
typedef __bf16 bf16x8 __attribute__((ext_vector_type(8)));
typedef float floatx4 __attribute__((ext_vector_type(4)));

static __device__ __forceinline__ bf16x8 load_bf8(const bf16* p) {
    return *reinterpret_cast<const bf16x8*>(p);
}

// ---------------- fp32 -> bf16 conversion of x and all weights ----------------
__global__ __launch_bounds__(256) void convert_kernel(
    const float* __restrict__ x, const float* __restrict__ wq,
    const float* __restrict__ wk, const float* __restrict__ wv,
    const float* __restrict__ wo,
    bf16* __restrict__ xb, bf16* __restrict__ wqb, bf16* __restrict__ wkb,
    bf16* __restrict__ wvb, bf16* __restrict__ wob) {
    int i = blockIdx.x * blockDim.x + threadIdx.x;  // one float4 per thread
    const float* src; bf16* dst; int off;
    if      (i < 1048576) { src = x;  dst = xb;  off = i; }
    else if (i < 2097152) { src = wq; dst = wqb; off = i - 1048576; }
    else if (i < 2359296) { src = wk; dst = wkb; off = i - 2097152; }
    else if (i < 2621440) { src = wv; dst = wvb; off = i - 2359296; }
    else if (i < 3670016) { src = wo; dst = wob; off = i - 2621440; }
    else return;
    float4 v = reinterpret_cast<const float4*>(src)[off];
    union { bf16 b[4]; ushort4 u; } t;
    t.b[0] = (bf16)v.x; t.b[1] = (bf16)v.y; t.b[2] = (bf16)v.z; t.b[3] = (bf16)v.w;
    reinterpret_cast<ushort4*>(dst)[off] = t.u;
}

// ---------------- QKV projection: qkv[m][n] = clip(x @ W^T), n in [0,3072) ----
__global__ __launch_bounds__(256) void gemm_qkv(
    const bf16* __restrict__ xb, const bf16* __restrict__ wqb,
    const bf16* __restrict__ wkb, const bf16* __restrict__ wvb,
    bf16* __restrict__ qkv) {
    int lane = threadIdx.x & 63;
    int wid  = threadIdx.x >> 6;
    int m0 = blockIdx.y * 64 + wid * 16;
    int n0 = blockIdx.x * 64;
    int l15 = lane & 15, quad = lane >> 4;

    const bf16* wrow[4];
#pragma unroll
    for (int ns = 0; ns < 4; ++ns) {
        int n = n0 + ns * 16 + l15;
        const bf16* w; int r;
        if (n < 2048) { w = wqb; r = n; }
        else if (n < 2560) { w = wkb; r = n - 2048; }
        else { w = wvb; r = n - 2560; }
        wrow[ns] = w + (size_t)r * 2048;
    }
    const bf16* arow = xb + (size_t)(m0 + l15) * 2048;

    floatx4 acc[4];
#pragma unroll
    for (int ns = 0; ns < 4; ++ns) acc[ns] = floatx4{0.f, 0.f, 0.f, 0.f};

    for (int k0 = 0; k0 < 2048; k0 += 32) {
        bf16x8 a = load_bf8(arow + k0 + quad * 8);
#pragma unroll
        for (int ns = 0; ns < 4; ++ns) {
            bf16x8 b = load_bf8(wrow[ns] + k0 + quad * 8);
            acc[ns] = __builtin_amdgcn_mfma_f32_16x16x32_bf16(a, b, acc[ns], 0, 0, 0);
        }
    }
#pragma unroll
    for (int ns = 0; ns < 4; ++ns)
#pragma unroll
        for (int r = 0; r < 4; ++r) {
            int m = m0 + quad * 4 + r;
            int n = n0 + ns * 16 + l15;
            float v = acc[ns][r];
            v = fminf(fmaxf(v, -8.0f), 8.0f);
            qkv[(size_t)m * 3072 + n] = (bf16)v;
        }
}

// ---------------- per-head RMSNorm + RoPE; V transposed copy -----------------
__global__ __launch_bounds__(128) void norm_rope(
    const bf16* __restrict__ qkv, const float* __restrict__ qw,
    const float* __restrict__ kw, bf16* __restrict__ qb,
    bf16* __restrict__ kb, bf16* __restrict__ vtb) {
    int s = blockIdx.x;
    int idx = blockIdx.y;      // 0..15 = q heads, 16..19 = k heads (+v copy)
    int d = threadIdx.x;       // 0..127
    bool isq = idx < 16;
    int off = isq ? idx * 128 : 2048 + (idx - 16) * 128;
    float val = (float)qkv[(size_t)s * 3072 + off + d];

    float ss = val * val;
#pragma unroll
    for (int o = 32; o > 0; o >>= 1) ss += __shfl_xor(ss, o, 64);
    __shared__ float wsum[2];
    __shared__ float xs[128];
    if ((threadIdx.x & 63) == 0) wsum[threadIdx.x >> 6] = ss;
    __syncthreads();
    float var = (wsum[0] + wsum[1]) * (1.0f / 128.0f);
    float nw = isq ? qw[d] : kw[d];
    float xn = val * rsqrtf(var + 1e-6f) * nw;
    xs[d] = xn;
    __syncthreads();
    float part = xs[d ^ 64];
    float rot = (d < 64) ? -part : part;
    int fi = d & 63;
    // inv_freq = theta^(-fi/64); ln(500000) = 13.122363377404328
    float inv = expf((float)fi * (-13.122363377404328f / 64.0f));
    float ang = (float)s * inv;
    float c = cosf(ang), sn = sinf(ang);
    float outv = xn * c + rot * sn;
    if (isq) {
        qb[(size_t)s * 2048 + idx * 128 + d] = (bf16)outv;
    } else {
        int kh = idx - 16;
        kb[(size_t)s * 512 + kh * 128 + d] = (bf16)outv;
        bf16 vv = qkv[(size_t)s * 3072 + 2560 + kh * 128 + d];
        vtb[((size_t)(kh * 128 + d)) * 2048 + s] = vv;  // V^T: [kvh*128+d][s]
    }
}

// ---------------- flash attention, sliding window + sink ---------------------
__global__ __launch_bounds__(256) void attn(
    const bf16* __restrict__ qb, const bf16* __restrict__ kb,
    const bf16* __restrict__ vtb, const float* __restrict__ sinks,
    bf16* __restrict__ attb) {
    int lane = threadIdx.x & 63;
    int wid  = threadIdx.x >> 6;
    int h = blockIdx.y;
    int kh = h >> 2;
    int qw0 = blockIdx.x * 64 + wid * 16;
    int l15 = lane & 15, quad = lane >> 4;

    __shared__ __align__(16) bf16 ldsp[4][16 * 32];
    bf16* myp = ldsp[wid];

    // Q fragments: A[m=l15][k=quad*8+j], 4 chunks of k=32 covering HD=128
    bf16x8 qf[4];
    const bf16* qrow = qb + (size_t)(qw0 + l15) * 2048 + h * 128 + quad * 8;
#pragma unroll
    for (int kc = 0; kc < 4; ++kc) qf[kc] = load_bf8(qrow + kc * 32);

    floatx4 acc[8];
#pragma unroll
    for (int f = 0; f < 8; ++f) acc[f] = floatx4{0.f, 0.f, 0.f, 0.f};
    float mrow[4], lrow[4];
#pragma unroll
    for (int r = 0; r < 4; ++r) { mrow[r] = -1e30f; lrow[r] = 0.0f; }

    int qi_base = qw0 + quad * 4;
    int start = qw0 - (WINDOW - 1); if (start < 0) start = 0;
    int t0 = start & ~31;

    for (int t = t0; t <= qw0 + 15; t += 32) {
        floatx4 s0 = floatx4{0.f, 0.f, 0.f, 0.f};
        floatx4 s1 = floatx4{0.f, 0.f, 0.f, 0.f};
        const bf16* k0r = kb + (size_t)(t + l15) * 512 + kh * 128 + quad * 8;
        const bf16* k1r = k0r + 16 * 512;
#pragma unroll
        for (int kc = 0; kc < 4; ++kc) {
            bf16x8 b0 = load_bf8(k0r + kc * 32);
            s0 = __builtin_amdgcn_mfma_f32_16x16x32_bf16(qf[kc], b0, s0, 0, 0, 0);
        }
#pragma unroll
        for (int kc = 0; kc < 4; ++kc) {
            bf16x8 b1 = load_bf8(k1r + kc * 32);
            s1 = __builtin_amdgcn_mfma_f32_16x16x32_bf16(qf[kc], b1, s1, 0, 0, 0);
        }
        int ki0 = t + l15, ki1 = ki0 + 16;
        float p0[4], p1[4], alpha[4];
#pragma unroll
        for (int r = 0; r < 4; ++r) {
            int qi = qi_base + r;
            float v0 = s0[r] * 0.08838834764831845f;  // 1/sqrt(128)
            float v1 = s1[r] * 0.08838834764831845f;
            bool ok0 = (ki0 <= qi) && (ki0 > qi - WINDOW);
            bool ok1 = (ki1 <= qi) && (ki1 > qi - WINDOW);
            v0 = ok0 ? v0 : -1e30f;
            v1 = ok1 ? v1 : -1e30f;
            float mt = fmaxf(v0, v1);
#pragma unroll
            for (int o = 1; o < 16; o <<= 1) mt = fmaxf(mt, __shfl_xor(mt, o, 64));
            float nm = fmaxf(mrow[r], mt);
            alpha[r] = __expf(mrow[r] - nm);
            mrow[r] = nm;
            float e0 = ok0 ? __expf(v0 - nm) : 0.0f;
            float e1 = ok1 ? __expf(v1 - nm) : 0.0f;
            p0[r] = e0; p1[r] = e1;
            float rs = e0 + e1;
#pragma unroll
            for (int o = 1; o < 16; o <<= 1) rs += __shfl_xor(rs, o, 64);
            lrow[r] = lrow[r] * alpha[r] + rs;
        }
#pragma unroll
        for (int f = 0; f < 8; ++f)
#pragma unroll
            for (int r = 0; r < 4; ++r) acc[f][r] *= alpha[r];

        // P (C-layout) -> LDS -> A-layout fragment (same wave, DS in-order)
#pragma unroll
        for (int r = 0; r < 4; ++r) {
            int row = quad * 4 + r;
            myp[row * 32 + l15]      = (bf16)p0[r];
            myp[row * 32 + 16 + l15] = (bf16)p1[r];
        }
        bf16x8 pa = load_bf8(myp + l15 * 32 + quad * 8);

        const bf16* vcol = vtb + ((size_t)(kh * 128 + l15)) * 2048 + t + quad * 8;
#pragma unroll
        for (int f = 0; f < 8; ++f) {
            bf16x8 vb = load_bf8(vcol + (size_t)f * 16 * 2048);
            acc[f] = __builtin_amdgcn_mfma_f32_16x16x32_bf16(pa, vb, acc[f], 0, 0, 0);
        }
    }

    // fold in sink logit, normalize, store att (bf16) in [s][h*128+d] layout
    float sk = sinks[h];
#pragma unroll
    for (int r = 0; r < 4; ++r) {
        float nm = fmaxf(mrow[r], sk);
        float sc = __expf(mrow[r] - nm);
        float l2 = lrow[r] * sc + __expf(sk - nm);
        float rs = sc / l2;
        int m = qw0 + quad * 4 + r;
#pragma unroll
        for (int f = 0; f < 8; ++f) {
            attb[(size_t)m * 2048 + h * 128 + f * 16 + l15] = (bf16)(acc[f][r] * rs);
        }
    }
}

// ---------------- output projection: out = att @ w_out^T (fp32 out) ----------
__global__ __launch_bounds__(256) void gemm_out(
    const bf16* __restrict__ attb, const bf16* __restrict__ wob,
    float* __restrict__ out) {
    int lane = threadIdx.x & 63;
    int wid  = threadIdx.x >> 6;
    int m0 = blockIdx.y * 64 + wid * 16;
    int n0 = blockIdx.x * 64;
    int l15 = lane & 15, quad = lane >> 4;
    const bf16* arow = attb + (size_t)(m0 + l15) * 2048;
    const bf16* brow[4];
#pragma unroll
    for (int ns = 0; ns < 4; ++ns)
        brow[ns] = wob + (size_t)(n0 + ns * 16 + l15) * 2048;
    floatx4 acc[4];
#pragma unroll
    for (int ns = 0; ns < 4; ++ns) acc[ns] = floatx4{0.f, 0.f, 0.f, 0.f};
    for (int k0 = 0; k0 < 2048; k0 += 32) {
        bf16x8 a = load_bf8(arow + k0 + quad * 8);
#pragma unroll
        for (int ns = 0; ns < 4; ++ns) {
            bf16x8 b = load_bf8(brow[ns] + k0 + quad * 8);
            acc[ns] = __builtin_amdgcn_mfma_f32_16x16x32_bf16(a, b, acc[ns], 0, 0, 0);
        }
    }
#pragma unroll
    for (int ns = 0; ns < 4; ++ns)
#pragma unroll
        for (int r = 0; r < 4; ++r)
            out[(size_t)(m0 + quad * 4 + r) * 2048 + n0 + ns * 16 + l15] = acc[ns][r];
}

extern "C" void kernel_launch(void* const* d_in, const int* in_sizes, int n_in,
                              void* d_out, int out_size, void* d_ws, size_t ws_size,
                              hipStream_t stream) {
    const float* x      = (const float*)d_in[0];
    const float* w_q    = (const float*)d_in[1];
    const float* w_k    = (const float*)d_in[2];
    const float* w_v    = (const float*)d_in[3];
    const float* w_out  = (const float*)d_in[4];
    const float* q_norm = (const float*)d_in[5];
    const float* k_norm = (const float*)d_in[6];
    const float* sinks  = (const float*)d_in[7];

    char* ws = (char*)d_ws;
    const size_t MB = 1u << 20;
    bf16* xb   = (bf16*)(ws + 0 * MB);    // 8 MB
    bf16* wqb  = (bf16*)(ws + 8 * MB);    // 8 MB
    bf16* wkb  = (bf16*)(ws + 16 * MB);   // 2 MB
    bf16* wvb  = (bf16*)(ws + 18 * MB);   // 2 MB
    bf16* wob  = (bf16*)(ws + 20 * MB);   // 8 MB
    bf16* qkv  = (bf16*)(ws + 28 * MB);   // 12 MB (S x 3072, post-clip)
    bf16* qb   = (bf16*)(ws + 40 * MB);   // 8 MB  (post norm+rope)
    bf16* kb   = (bf16*)(ws + 48 * MB);   // 2 MB
    bf16* vtb  = (bf16*)(ws + 50 * MB);   // 2 MB  (V transposed)
    bf16* attb = (bf16*)(ws + 52 * MB);   // 8 MB
    float* out = (float*)d_out;

    convert_kernel<<<14336, 256, 0, stream>>>(x, w_q, w_k, w_v, w_out,
                                              xb, wqb, wkb, wvb, wob);
    gemm_qkv<<<dim3(48, 32), 256, 0, stream>>>(xb, wqb, wkb, wvb, qkv);
    norm_rope<<<dim3(2048, 20), 128, 0, stream>>>(qkv, q_norm, k_norm, qb, kb, vtb);
    attn<<<dim3(32, 16), 256, 0, stream>>>(qb, kb, vtb, sinks, attb);
    gemm_out<<<dim3(32, 32), 256, 0, stream>>>(attb, wob, out);
}

// Round 3
// 343.752 us; speedup vs baseline: 1.7356x; 1.7356x over previous
//
#include <hip/hip_runtime.h>
#include <hip/hip_bf16.h>
#include <math.h>

#define S_LEN 2048
#define DMODEL 2048
#define NH 16
#define NKVH 4
#define HDIM 128
#define WINDOW 1024

typedef __bf16 bf16;
typedef __bf16 bf16x8 __attribute__((ext_vector_type(8)));
typedef float floatx4 __attribute__((ext_vector_type(4)));

static __device__ __forceinline__ bf16x8 load_bf8(const bf16* p) {
    return *reinterpret_cast<const bf16x8*>(p);
}

// async 16B global->LDS (wave-uniform LDS base + lane*16)
static __device__ __forceinline__ void async16(const bf16* g, bf16* l) {
    __builtin_amdgcn_global_load_lds(
        (const __attribute__((address_space(1))) void*)g,
        (__attribute__((address_space(3))) void*)l, 16, 0, 0);
}

// ---------------- fp32 -> bf16 conversion of x and all weights ----------------
__global__ __launch_bounds__(256) void convert_kernel(
    const float* __restrict__ x, const float* __restrict__ wq,
    const float* __restrict__ wk, const float* __restrict__ wv,
    const float* __restrict__ wo,
    bf16* __restrict__ xb, bf16* __restrict__ wqb, bf16* __restrict__ wkb,
    bf16* __restrict__ wvb, bf16* __restrict__ wob) {
    int i = blockIdx.x * blockDim.x + threadIdx.x;  // one float4 per thread
    const float* src; bf16* dst; int off;
    if      (i < 1048576) { src = x;  dst = xb;  off = i; }
    else if (i < 2097152) { src = wq; dst = wqb; off = i - 1048576; }
    else if (i < 2359296) { src = wk; dst = wkb; off = i - 2097152; }
    else if (i < 2621440) { src = wv; dst = wvb; off = i - 2359296; }
    else if (i < 3670016) { src = wo; dst = wob; off = i - 2621440; }
    else return;
    float4 v = reinterpret_cast<const float4*>(src)[off];
    union { bf16 b[4]; ushort4 u; } t;
    t.b[0] = (bf16)v.x; t.b[1] = (bf16)v.y; t.b[2] = (bf16)v.z; t.b[3] = (bf16)v.w;
    reinterpret_cast<ushort4*>(dst)[off] = t.u;
}

// ---------------- 128x128-tile GEMM: C = A @ B^T (m97 structure) -------------
// A: [M][K] bf16, B: [N][K] bf16, C: [M][N] OutT. K multiple of 32,
// M,N multiples of 128. 256 threads = 4 waves, each wave computes 64x64.
template <bool CLIP, typename OutT>
__global__ __launch_bounds__(256) void gemm128(
    const bf16* __restrict__ A, const bf16* __restrict__ B,
    OutT* __restrict__ C, int N, int K) {
    __shared__ __align__(16) bf16 sA[128 * 32];  // 8 KB, row-major [128][32]
    __shared__ __align__(16) bf16 sB[128 * 32];  // 8 KB
    int tid = threadIdx.x;
    int lane = tid & 63, wid = tid >> 6;
    int l15 = lane & 15, quad = lane >> 4;
    int m0 = blockIdx.y * 128, n0 = blockIdx.x * 128;

    // staging: thread covers (row = wid*16 + lane/4 [+64], col = (lane&3)*8)
    int srow = wid * 16 + (lane >> 2);
    int scol = (lane & 3) * 8;
    const bf16* gA0 = A + (size_t)(m0 + srow) * K + scol;
    const bf16* gA1 = gA0 + (size_t)64 * K;
    const bf16* gB0 = B + (size_t)(n0 + srow) * K + scol;
    const bf16* gB1 = gB0 + (size_t)64 * K;
    bf16* lA0 = sA + (wid * 16) * 32;        // wave-uniform bases
    bf16* lA1 = sA + (64 + wid * 16) * 32;
    bf16* lB0 = sB + (wid * 16) * 32;
    bf16* lB1 = sB + (64 + wid * 16) * 32;

    floatx4 acc[4][4];
#pragma unroll
    for (int mi = 0; mi < 4; ++mi)
#pragma unroll
        for (int ni = 0; ni < 4; ++ni) acc[mi][ni] = floatx4{0.f, 0.f, 0.f, 0.f};

    int mb = (wid & 1) * 64, nb = (wid >> 1) * 64;

    for (int k0 = 0; k0 < K; k0 += 32) {
        async16(gA0 + k0, lA0);
        async16(gA1 + k0, lA1);
        async16(gB0 + k0, lB0);
        async16(gB1 + k0, lB1);
        __syncthreads();   // drains vmcnt (global_load_lds) + orders LDS
        bf16x8 af[4], bq[4];
#pragma unroll
        for (int i = 0; i < 4; ++i) {
            af[i] = load_bf8(sA + (mb + i * 16 + l15) * 32 + quad * 8);
            bq[i] = load_bf8(sB + (nb + i * 16 + l15) * 32 + quad * 8);
        }
#pragma unroll
        for (int mi = 0; mi < 4; ++mi)
#pragma unroll
            for (int ni = 0; ni < 4; ++ni)
                acc[mi][ni] = __builtin_amdgcn_mfma_f32_16x16x32_bf16(
                    af[mi], bq[ni], acc[mi][ni], 0, 0, 0);
        __syncthreads();   // all waves done reading before next stage
    }

#pragma unroll
    for (int mi = 0; mi < 4; ++mi)
#pragma unroll
        for (int ni = 0; ni < 4; ++ni)
#pragma unroll
            for (int r = 0; r < 4; ++r) {
                int m = m0 + mb + mi * 16 + quad * 4 + r;
                int n = n0 + nb + ni * 16 + l15;
                float v = acc[mi][ni][r];
                if (CLIP) v = fminf(fmaxf(v, -8.0f), 8.0f);
                C[(size_t)m * N + n] = (OutT)v;
            }
}

// ---------------- per-head RMSNorm + RoPE; V transposed copy -----------------
__global__ __launch_bounds__(128) void norm_rope(
    const bf16* __restrict__ qkv, const float* __restrict__ qw,
    const float* __restrict__ kw, bf16* __restrict__ qb,
    bf16* __restrict__ kb, bf16* __restrict__ vtb) {
    int s = blockIdx.x;
    int idx = blockIdx.y;      // 0..15 = q heads, 16..19 = k heads (+v copy)
    int d = threadIdx.x;       // 0..127
    bool isq = idx < 16;
    int off = isq ? idx * 128 : 2048 + (idx - 16) * 128;
    float val = (float)qkv[(size_t)s * 3072 + off + d];

    float ss = val * val;
#pragma unroll
    for (int o = 32; o > 0; o >>= 1) ss += __shfl_xor(ss, o, 64);
    __shared__ float wsum[2];
    __shared__ float xs[128];
    if ((threadIdx.x & 63) == 0) wsum[threadIdx.x >> 6] = ss;
    __syncthreads();
    float var = (wsum[0] + wsum[1]) * (1.0f / 128.0f);
    float nw = isq ? qw[d] : kw[d];
    float xn = val * rsqrtf(var + 1e-6f) * nw;
    xs[d] = xn;
    __syncthreads();
    float part = xs[d ^ 64];
    float rot = (d < 64) ? -part : part;
    int fi = d & 63;
    // inv_freq = theta^(-fi/64); ln(500000) = 13.122363377404328
    float inv = expf((float)fi * (-13.122363377404328f / 64.0f));
    float ang = (float)s * inv;
    float c = cosf(ang), sn = sinf(ang);
    float outv = xn * c + rot * sn;
    if (isq) {
        qb[(size_t)s * 2048 + idx * 128 + d] = (bf16)outv;
    } else {
        int kh = idx - 16;
        kb[(size_t)s * 512 + kh * 128 + d] = (bf16)outv;
        bf16 vv = qkv[(size_t)s * 3072 + 2560 + kh * 128 + d];
        vtb[((size_t)(kh * 128 + d)) * 2048 + s] = vv;  // V^T: [kvh*128+d][s]
    }
}

// ---------------- flash attention, sliding window + sink ---------------------
__global__ __launch_bounds__(256) void attn(
    const bf16* __restrict__ qb, const bf16* __restrict__ kb,
    const bf16* __restrict__ vtb, const float* __restrict__ sinks,
    bf16* __restrict__ attb) {
    int lane = threadIdx.x & 63;
    int wid  = threadIdx.x >> 6;
    int h = blockIdx.y;
    int kh = h >> 2;
    int qw0 = blockIdx.x * 64 + wid * 16;
    int l15 = lane & 15, quad = lane >> 4;

    __shared__ __align__(16) bf16 ldsp[4][16 * 32];
    bf16* myp = ldsp[wid];

    // Q fragments: A[m=l15][k=quad*8+j], 4 chunks of k=32 covering HD=128
    bf16x8 qf[4];
    const bf16* qrow = qb + (size_t)(qw0 + l15) * 2048 + h * 128 + quad * 8;
#pragma unroll
    for (int kc = 0; kc < 4; ++kc) qf[kc] = load_bf8(qrow + kc * 32);

    floatx4 acc[8];
#pragma unroll
    for (int f = 0; f < 8; ++f) acc[f] = floatx4{0.f, 0.f, 0.f, 0.f};
    float mrow[4], lrow[4];
#pragma unroll
    for (int r = 0; r < 4; ++r) { mrow[r] = -1e30f; lrow[r] = 0.0f; }

    int qi_base = qw0 + quad * 4;
    int start = qw0 - (WINDOW - 1); if (start < 0) start = 0;
    int t0 = start & ~31;

    for (int t = t0; t <= qw0 + 15; t += 32) {
        floatx4 s0 = floatx4{0.f, 0.f, 0.f, 0.f};
        floatx4 s1 = floatx4{0.f, 0.f, 0.f, 0.f};
        const bf16* k0r = kb + (size_t)(t + l15) * 512 + kh * 128 + quad * 8;
        const bf16* k1r = k0r + 16 * 512;
#pragma unroll
        for (int kc = 0; kc < 4; ++kc) {
            bf16x8 b0 = load_bf8(k0r + kc * 32);
            s0 = __builtin_amdgcn_mfma_f32_16x16x32_bf16(qf[kc], b0, s0, 0, 0, 0);
        }
#pragma unroll
        for (int kc = 0; kc < 4; ++kc) {
            bf16x8 b1 = load_bf8(k1r + kc * 32);
            s1 = __builtin_amdgcn_mfma_f32_16x16x32_bf16(qf[kc], b1, s1, 0, 0, 0);
        }
        int ki0 = t + l15, ki1 = ki0 + 16;
        float p0[4], p1[4], alpha[4];
#pragma unroll
        for (int r = 0; r < 4; ++r) {
            int qi = qi_base + r;
            float v0 = s0[r] * 0.08838834764831845f;  // 1/sqrt(128)
            float v1 = s1[r] * 0.08838834764831845f;
            bool ok0 = (ki0 <= qi) && (ki0 > qi - WINDOW);
            bool ok1 = (ki1 <= qi) && (ki1 > qi - WINDOW);
            v0 = ok0 ? v0 : -1e30f;
            v1 = ok1 ? v1 : -1e30f;
            float mt = fmaxf(v0, v1);
#pragma unroll
            for (int o = 1; o < 16; o <<= 1) mt = fmaxf(mt, __shfl_xor(mt, o, 64));
            float nm = fmaxf(mrow[r], mt);
            alpha[r] = __expf(mrow[r] - nm);
            mrow[r] = nm;
            float e0 = ok0 ? __expf(v0 - nm) : 0.0f;
            float e1 = ok1 ? __expf(v1 - nm) : 0.0f;
            p0[r] = e0; p1[r] = e1;
            float rs = e0 + e1;
#pragma unroll
            for (int o = 1; o < 16; o <<= 1) rs += __shfl_xor(rs, o, 64);
            lrow[r] = lrow[r] * alpha[r] + rs;
        }
#pragma unroll
        for (int f = 0; f < 8; ++f)
#pragma unroll
            for (int r = 0; r < 4; ++r) acc[f][r] *= alpha[r];

        // P (C-layout) -> LDS -> A-layout fragment (same wave, DS in-order)
#pragma unroll
        for (int r = 0; r < 4; ++r) {
            int row = quad * 4 + r;
            myp[row * 32 + l15]      = (bf16)p0[r];
            myp[row * 32 + 16 + l15] = (bf16)p1[r];
        }
        bf16x8 pa = load_bf8(myp + l15 * 32 + quad * 8);

        const bf16* vcol = vtb + ((size_t)(kh * 128 + l15)) * 2048 + t + quad * 8;
#pragma unroll
        for (int f = 0; f < 8; ++f) {
            bf16x8 vb = load_bf8(vcol + (size_t)f * 16 * 2048);
            acc[f] = __builtin_amdgcn_mfma_f32_16x16x32_bf16(pa, vb, acc[f], 0, 0, 0);
        }
    }

    // fold in sink logit, normalize, store att (bf16) in [s][h*128+d] layout
    float sk = sinks[h];
#pragma unroll
    for (int r = 0; r < 4; ++r) {
        float nm = fmaxf(mrow[r], sk);
        float sc = __expf(mrow[r] - nm);
        float l2 = lrow[r] * sc + __expf(sk - nm);
        float rs = sc / l2;
        int m = qw0 + quad * 4 + r;
#pragma unroll
        for (int f = 0; f < 8; ++f) {
            attb[(size_t)m * 2048 + h * 128 + f * 16 + l15] = (bf16)(acc[f][r] * rs);
        }
    }
}

extern "C" void kernel_launch(void* const* d_in, const int* in_sizes, int n_in,
                              void* d_out, int out_size, void* d_ws, size_t ws_size,
                              hipStream_t stream) {
    const float* x      = (const float*)d_in[0];
    const float* w_q    = (const float*)d_in[1];
    const float* w_k    = (const float*)d_in[2];
    const float* w_v    = (const float*)d_in[3];
    const float* w_out  = (const float*)d_in[4];
    const float* q_norm = (const float*)d_in[5];
    const float* k_norm = (const float*)d_in[6];
    const float* sinks  = (const float*)d_in[7];

    char* ws = (char*)d_ws;
    const size_t MB = 1u << 20;
    bf16* xb   = (bf16*)(ws + 0 * MB);    // 8 MB
    bf16* wqb  = (bf16*)(ws + 8 * MB);    // 8 MB  (wqb/wkb/wvb contiguous)
    bf16* wkb  = (bf16*)(ws + 16 * MB);   // 2 MB  (forms wcomb [3072][2048])
    bf16* wvb  = (bf16*)(ws + 18 * MB);   // 2 MB
    bf16* wob  = (bf16*)(ws + 20 * MB);   // 8 MB
    bf16* qkv  = (bf16*)(ws + 28 * MB);   // 12 MB (S x 3072, post-clip)
    bf16* qb   = (bf16*)(ws + 40 * MB);   // 8 MB  (post norm+rope)
    bf16* kb   = (bf16*)(ws + 48 * MB);   // 2 MB
    bf16* vtb  = (bf16*)(ws + 50 * MB);   // 2 MB  (V transposed)
    bf16* attb = (bf16*)(ws + 52 * MB);   // 8 MB
    bf16* wcomb = wqb;                    // rows 0..3071 = [w_q; w_k; w_v]
    float* out = (float*)d_out;

    convert_kernel<<<14336, 256, 0, stream>>>(x, w_q, w_k, w_v, w_out,
                                              xb, wqb, wkb, wvb, wob);
    gemm128<true, bf16><<<dim3(24, 16), 256, 0, stream>>>(xb, wcomb, qkv, 3072, 2048);
    norm_rope<<<dim3(2048, 20), 128, 0, stream>>>(qkv, q_norm, k_norm, qb, kb, vtb);
    attn<<<dim3(32, 16), 256, 0, stream>>>(qb, kb, vtb, sinks, attb);
    gemm128<false, float><<<dim3(16, 16), 256, 0, stream>>>(attb, wob, out, 2048, 2048);
}